// Round 11
// baseline (35.515 us; speedup 1.0000x reference)
//
#include <hip/hip_runtime.h>

// AdLIF neuron scan, fused producer/consumer/writer single kernel.
// Round 11: 32 channels per block -> 1024 blocks -> 4 blocks/CU (32 waves/CU,
// the occupancy cap), doubling concurrent memory-issuing waves per CU vs
// round 10 (whose 512-block grid capped the machine at 2 blocks/CU no matter
// how small LDS got).
//
// 1024 blocks x 512 threads (8 waves), one block owns 32 channels (b, dgrp):
//   wave 0   : consumer -- 512-step recurrence (32 active lanes) reading
//              x-tiles from a 3-deep LDS ring, bitpacking spikes into a tiny
//              LDS double-buffer.
//   waves 1-3: producers -- stage 64t x 32ch x-tiles into the ring with
//              dwordx4 loads (8x128B segments per instr), 2 tiles ahead.
//   waves 4-7: writers -- expand tile k-1's bits to f32, float4 NT stores.
// One __syncthreads per tile; 9 pipelined iterations (8 tiles + drain).
//
// FP order matches the JAX reference exactly (mul then add, round-to-nearest,
// NO fma contraction) so spike decisions are bit-stable vs the reference.

#define T_STEPS 512
#define D_DIM   1024
#define CH      32                   // channels per block
#define T_TILE  64
#define N_TILES (T_STEPS / T_TILE)   // 8
#define RING    3
#define LDS_PITCH 34                 // 32 + 2 pad (dwords)

// f32(np.exp(-1/20)), f32(np.exp(-1/200))
#define ALPHA_MEM 0.9512294245007141f
#define ALPHA_ADP 0.9950124791926823f

typedef float f32x4 __attribute__((ext_vector_type(4)));

__device__ __forceinline__ bool adlif_step(float xv, float& v, float& a) {
    // v = alpha_mem * v + x_t
    v = __fadd_rn(__fmul_rn(ALPHA_MEM, v), xv);
    // cur_thr = THRESHOLD + BETA * a  (1.0 + 0.1*a)
    float cur = __fadd_rn(1.0f, __fmul_rn(0.1f, a));
    // s = (v - cur_thr >= THRESHOLD)   -- threshold counts twice, per ref
    float u = __fsub_rn(v, cur);
    bool fired = (u >= 1.0f);
    float s = fired ? 1.0f : 0.0f;
    // a = alpha_adp * a + s
    a = __fadd_rn(__fmul_rn(ALPHA_ADP, a), s);
    // v = v - s * THRESHOLD  (THRESHOLD = 1, exact)
    v = __fsub_rn(v, s);
    return fired;
}

// Producer: load one 64t x 32ch tile with 8 dwordx4 loads per wave.
// Lane L: rows r0=L>>3 (+8 per instr), channels m=(L&7)*4 .. +3 (16B/lane).
__device__ __forceinline__ void load_tile(const float* __restrict__ xb, int t0,
                                          int lane, float (*buf)[LDS_PITCH]) {
    const int r0 = lane >> 3;            // 0..7
    const int m  = lane & 7;             // 0..7
    const float* src = xb + (size_t)(t0 + r0) * D_DIM + m * 4;
    f32x4 v[8];
#pragma unroll
    for (int i = 0; i < 8; ++i)
        v[i] = *reinterpret_cast<const f32x4*>(src + (size_t)i * 8 * D_DIM);
#pragma unroll
    for (int i = 0; i < 8; ++i)
        *reinterpret_cast<f32x4*>(&buf[i * 8 + r0][m * 4]) = v[i];
}

__global__ __launch_bounds__(512) void adlif_fused(const float* __restrict__ x,
                                                   float* __restrict__ out) {
    __shared__ float    tiles[RING][T_TILE][LDS_PITCH]; // 26112 B input ring
    __shared__ unsigned sbits[2][CH][2];                // 512 B spike-bit dbuf

    const int lane = threadIdx.x & 63;
    const int wave = threadIdx.x >> 6;               // 0..7
    const int bid  = blockIdx.x;                     // 0..1023
    const int b    = bid >> 5;                       // 0..31
    const int dgrp = bid & 31;                       // 0..31
    const float* xb = x   + (size_t)b * (T_STEPS * D_DIM) + dgrp * CH;
    float*       ob = out + (size_t)b * (T_STEPS * D_DIM) + dgrp * CH;

    // prologue: producers fill tiles 0,1 (lookahead 2)
    if (wave == 1) load_tile(xb, 0 * T_TILE, lane, tiles[0]);
    if (wave == 2) load_tile(xb, 1 * T_TILE, lane, tiles[1]);
    __syncthreads();

    float v = 0.0f, a = 0.0f;

    for (int k = 0; k <= N_TILES; ++k) {             // 9 pipelined iterations
        if (wave == 0) {
            // ---- consumer: 64 steps of tile k -> 2 packed words in LDS ----
            if (k < N_TILES && lane < CH) {
                unsigned wlo = 0u, whi = 0u;
#pragma unroll
                for (int j = 0; j < T_TILE; ++j) {
                    const float xv = tiles[k % RING][j][lane];
                    const bool f = adlif_step(xv, v, a);
                    if (j < 32) wlo |= ((unsigned)f) << j;
                    else        whi |= ((unsigned)f) << (j - 32);
                }
                sbits[k & 1][lane][0] = wlo;
                sbits[k & 1][lane][1] = whi;
            }
        } else if (wave <= 3) {
            // ---- producer: stage tile k+2 into ring slot (k+2)%3 ----
            const int t = k + 2;
            if (t < N_TILES && wave == (t % 3) + 1)
                load_tile(xb, t * T_TILE, lane, tiles[t % RING]);
        } else {
            // ---- writers: expand tile k-1 bits -> f32, NT float4 stores ----
            if (k >= 1) {
                const int kt = k - 1;
                const int r0 = (wave - 4) * 16;      // this wave's 16 rows
                const int c0 = (lane & 7) * 4;       // 4 channels per lane
                const int rl = lane >> 3;            // 0..7 row-within-instr
                const int half = (r0 >= 32) ? 1 : 0; // wlo or whi
                const unsigned w0 = sbits[kt & 1][c0 + 0][half];
                const unsigned w1 = sbits[kt & 1][c0 + 1][half];
                const unsigned w2 = sbits[kt & 1][c0 + 2][half];
                const unsigned w3 = sbits[kt & 1][c0 + 3][half];
#pragma unroll
                for (int i = 0; i < 2; ++i) {
                    const int r = r0 + i * 8 + rl;   // absolute row in tile
                    const int bitpos = r & 31;
                    f32x4 val;
                    val.x = (float)((w0 >> bitpos) & 1u);
                    val.y = (float)((w1 >> bitpos) & 1u);
                    val.z = (float)((w2 >> bitpos) & 1u);
                    val.w = (float)((w3 >> bitpos) & 1u);
                    __builtin_nontemporal_store(
                        val, (f32x4*)(ob + (size_t)(kt * T_TILE + r) * D_DIM + c0));
                }
            }
        }
        __syncthreads();
    }
}

extern "C" void kernel_launch(void* const* d_in, const int* in_sizes, int n_in,
                              void* d_out, int out_size, void* d_ws, size_t ws_size,
                              hipStream_t stream) {
    const float* x = (const float*)d_in[0];
    float* out = (float*)d_out;

    const int total = in_sizes[0];            // B*T*D = 16777216
    const int channels = total / T_STEPS;     // B*D  = 32768
    const int blocks = channels / CH;         // 1024 blocks x 8 waves

    adlif_fused<<<blocks, 512, 0, stream>>>(x, out);
}

// Round 12
// 26.830 us; speedup vs baseline: 1.3237x; 1.3237x over previous
//
#include <hip/hip_runtime.h>

// AdLIF neuron scan, fused producer/consumer/writer single kernel.
// Round 12 ("smoothness bundle" on the r10 best-known structure):
//   - T_TILE 64 -> 32: pipeline fill/drain shrinks from 2/9 to 2/17 of
//     runtime; per-period burst halves to 16 KB/block.
//   - Each tile's 8 dwordx4 loads are split across ALL 3 producer waves
//     (static 3/3/2 instruction sets) -> 3 vmem FIFOs issue concurrently
//     every period instead of 1-of-3 rotating (r10 left 2 waves idle).
//   - LDS ~25 KB.
// 512 blocks x 512 threads (8 waves), one block owns 64 channels:
//   wave 0   : consumer -- recurrence from LDS ring, bitpacks 1 u32/period.
//   waves 1-3: producers -- cooperative tile staging, 2 tiles ahead.
//   waves 4-7: writers -- expand tile k-1 bits -> f32, float4 NT stores.
//
// FP order matches the JAX reference exactly (mul then add, round-to-nearest,
// NO fma contraction) so spike decisions are bit-stable vs the reference.

#define T_STEPS 512
#define D_DIM   1024
#define T_TILE  32
#define N_TILES (T_STEPS / T_TILE)   // 16
#define RING    3
#define LDS_PITCH 66                 // 64 + 2 pad (dwords)

// f32(np.exp(-1/20)), f32(np.exp(-1/200))
#define ALPHA_MEM 0.9512294245007141f
#define ALPHA_ADP 0.9950124791926823f

typedef float f32x4 __attribute__((ext_vector_type(4)));

__device__ __forceinline__ bool adlif_step(float xv, float& v, float& a) {
    // v = alpha_mem * v + x_t
    v = __fadd_rn(__fmul_rn(ALPHA_MEM, v), xv);
    // cur_thr = THRESHOLD + BETA * a  (1.0 + 0.1*a)
    float cur = __fadd_rn(1.0f, __fmul_rn(0.1f, a));
    // s = (v - cur_thr >= THRESHOLD)   -- threshold counts twice, per ref
    float u = __fsub_rn(v, cur);
    bool fired = (u >= 1.0f);
    float s = fired ? 1.0f : 0.0f;
    // a = alpha_adp * a + s
    a = __fadd_rn(__fmul_rn(ALPHA_ADP, a), s);
    // v = v - s * THRESHOLD  (THRESHOLD = 1, exact)
    v = __fsub_rn(v, s);
    return fired;
}

// Producer share: instruction indices {S, S+3, S+6, ...} of the tile's 8
// dwordx4 loads (S=0 -> 3 instrs, S=1 -> 3, S=2 -> 2). Static trip counts,
// no runtime-indexed register arrays.
// Instr i: rows i*4 + (lane>>4), channels (lane&15)*4 .. +3 (256B/row-seg).
template<int S>
__device__ __forceinline__ void load_tile_part(const float* __restrict__ xb, int t0,
                                               int lane, float (*buf)[LDS_PITCH]) {
    const int r0 = lane >> 4;            // 0..3
    const int m  = lane & 15;            // 0..15
    const float* src = xb + (size_t)(t0 + r0) * D_DIM + m * 4;
    constexpr int N = (8 - S + 2) / 3;
    f32x4 v[N];
#pragma unroll
    for (int j = 0; j < N; ++j)
        v[j] = *reinterpret_cast<const f32x4*>(src + (size_t)(S + 3 * j) * 4 * D_DIM);
#pragma unroll
    for (int j = 0; j < N; ++j)
        *reinterpret_cast<f32x4*>(&buf[(S + 3 * j) * 4 + r0][m * 4]) = v[j];
}

__global__ __launch_bounds__(512) void adlif_fused(const float* __restrict__ x,
                                                   float* __restrict__ out) {
    __shared__ float    tiles[RING][T_TILE][LDS_PITCH]; // 25344 B input ring
    __shared__ unsigned sbits[2][64];                   // spike-bit dbuf

    const int lane = threadIdx.x & 63;
    const int wave = threadIdx.x >> 6;               // 0..7
    const int bid  = blockIdx.x;                     // 0..511
    const int b    = bid >> 4;                       // 0..31
    const int dgrp = bid & 15;                       // 0..15
    const float* xb = x   + (size_t)b * (T_STEPS * D_DIM) + dgrp * 64;
    float*       ob = out + (size_t)b * (T_STEPS * D_DIM) + dgrp * 64;

    // prologue: all 3 producers cooperatively fill tiles 0 and 1 (lookahead 2)
    if (wave == 1) {
        load_tile_part<0>(xb, 0 * T_TILE, lane, tiles[0]);
        load_tile_part<0>(xb, 1 * T_TILE, lane, tiles[1]);
    } else if (wave == 2) {
        load_tile_part<1>(xb, 0 * T_TILE, lane, tiles[0]);
        load_tile_part<1>(xb, 1 * T_TILE, lane, tiles[1]);
    } else if (wave == 3) {
        load_tile_part<2>(xb, 0 * T_TILE, lane, tiles[0]);
        load_tile_part<2>(xb, 1 * T_TILE, lane, tiles[1]);
    }
    __syncthreads();

    float v = 0.0f, a = 0.0f;

    for (int k = 0; k <= N_TILES; ++k) {             // 17 pipelined iterations
        if (wave == 0) {
            // ---- consumer: 32 steps of tile k -> 1 packed word in LDS ----
            if (k < N_TILES) {
                unsigned w = 0u;
#pragma unroll
                for (int j = 0; j < T_TILE; ++j) {
                    const float xv = tiles[k % RING][j][lane];
                    const bool f = adlif_step(xv, v, a);
                    w |= ((unsigned)f) << j;
                }
                sbits[k & 1][lane] = w;
            }
        } else if (wave <= 3) {
            // ---- producers: cooperatively stage tile k+2 into slot (k+2)%3 ----
            const int t = k + 2;
            if (t < N_TILES) {
                if (wave == 1)      load_tile_part<0>(xb, t * T_TILE, lane, tiles[t % RING]);
                else if (wave == 2) load_tile_part<1>(xb, t * T_TILE, lane, tiles[t % RING]);
                else                load_tile_part<2>(xb, t * T_TILE, lane, tiles[t % RING]);
            }
        } else {
            // ---- writers: expand tile k-1 bits -> f32, NT float4 stores ----
            if (k >= 1) {
                const int kt = k - 1;
                const int r0 = (wave - 4) * 8;       // this wave's 8 rows
                const int c0 = (lane & 15) * 4;      // 4 channels per lane
                const int rl = lane >> 4;            // 0..3 row-within-instr
                const unsigned w0 = sbits[kt & 1][c0 + 0];
                const unsigned w1 = sbits[kt & 1][c0 + 1];
                const unsigned w2 = sbits[kt & 1][c0 + 2];
                const unsigned w3 = sbits[kt & 1][c0 + 3];
#pragma unroll
                for (int i = 0; i < 2; ++i) {
                    const int r = r0 + i * 4 + rl;   // absolute row in tile
                    f32x4 val;
                    val.x = (float)((w0 >> r) & 1u);
                    val.y = (float)((w1 >> r) & 1u);
                    val.z = (float)((w2 >> r) & 1u);
                    val.w = (float)((w3 >> r) & 1u);
                    __builtin_nontemporal_store(
                        val, (f32x4*)(ob + (size_t)(kt * T_TILE + r) * D_DIM + c0));
                }
            }
        }
        __syncthreads();
    }
}

extern "C" void kernel_launch(void* const* d_in, const int* in_sizes, int n_in,
                              void* d_out, int out_size, void* d_ws, size_t ws_size,
                              hipStream_t stream) {
    const float* x = (const float*)d_in[0];
    float* out = (float*)d_out;

    const int total = in_sizes[0];            // B*T*D = 16777216
    const int channels = total / T_STEPS;     // B*D  = 32768
    const int blocks = channels / 64;         // 512 blocks x 8 waves

    adlif_fused<<<blocks, 512, 0, stream>>>(x, out);
}